// Round 7
// baseline (559.920 us; speedup 1.0000x reference)
//
#include <hip/hip_runtime.h>
#include <hip/hip_bf16.h>
#include <math.h>

typedef __attribute__((ext_vector_type(8))) short short8;
typedef __attribute__((ext_vector_type(4))) float f32x4;
typedef __attribute__((ext_vector_type(16))) float f32x16;
typedef __attribute__((ext_vector_type(4))) unsigned short u16x4;
typedef __attribute__((ext_vector_type(8))) unsigned short u16x8;
typedef __attribute__((ext_vector_type(4))) unsigned int u32x4;
typedef __attribute__((ext_vector_type(2))) int i32x2;
typedef unsigned short u16;
typedef unsigned int u32;

#define DM 2048
#define SQ 2048
#define NB 4
#define NH 16
#define DKH 128
#define KT 64
#define NT (SQ / KT)
#define LD3 (3 * DM)
#define QSCALE (0.08838834764831845f * 1.4426950408889634f)

__device__ __forceinline__ u16 f2bf(float f) {
  unsigned u = __float_as_uint(f);
  u += 0x7fffu + ((u >> 16) & 1u);
  return (u16)(u >> 16);
}

__device__ __forceinline__ u32 cvtpk(float lo, float hi) {
  u32 r;
  asm("v_cvt_pk_bf16_f32 %0, %1, %2" : "=v"(r) : "v"(lo), "v"(hi));
  return r;
}

__device__ __forceinline__ void gload16(const u16* g, u16* lds) {
  __builtin_amdgcn_global_load_lds(
      (const __attribute__((address_space(1))) unsigned int*)g,
      (__attribute__((address_space(3))) unsigned int*)lds, 16, 0, 0);
}

__global__ void cvt_bf16(const float* __restrict__ in, u16* __restrict__ out, int n) {
  int i = (blockIdx.x * blockDim.x + threadIdx.x) * 4;
  if (i >= n) return;
  float4 v = *(const float4*)(in + i);
  u16x4 o;
  o.x = f2bf(v.x); o.y = f2bf(v.y); o.z = f2bf(v.z); o.w = f2bf(v.w);
  *(u16x4*)(out + i) = o;
}

// 4 weight matrices -> contiguous bf16 dst (blockIdx.y selects source)
__global__ void cvt_w4(const float* __restrict__ w0, const float* __restrict__ w1,
                       const float* __restrict__ w2, const float* __restrict__ w3,
                       u16* __restrict__ dst) {
  const int sel = blockIdx.y;
  const float* src;
  switch (sel) {
    case 0: src = w0; break;
    case 1: src = w1; break;
    case 2: src = w2; break;
    default: src = w3; break;
  }
  const int i = (blockIdx.x * blockDim.x + threadIdx.x) * 4;
  float4 v = *(const float4*)(src + i);
  u16x4 o;
  o.x = f2bf(v.x); o.y = f2bf(v.y); o.z = f2bf(v.z); o.w = f2bf(v.w);
  *(u16x4*)(dst + (size_t)sel * DM * DM + i) = o;
}

// ---------------- 256x256 8-phase pipelined GEMM ----------------
// MODE 0: fused QKV — C bf16 [M][N=6144]; bias/scale per 2048-col segment.
// MODE 1: single — C f32 [M][N], bias = bq.
// No forced lgkmcnt(0): compiler inserts per-dependency waits so MFMA overlaps
// the DS-read drain (the round-6 forced drain serialized the two pipes).

#define STG_A(T, HALF)                                                \
  do {                                                                \
    u16* d_ = &smA[((T) & 1) * 16384 + (((HALF) * 128 + w * 16) << 6)]; \
    const u16* s_ = As + (size_t)((HALF) * 128) * K + (size_t)(T) * 64; \
    gload16(s_, d_);                                                  \
    gload16(s_ + (size_t)8 * K, d_ + 8 * 64);                         \
  } while (0)

#define STG_B(T, HALF)                                                \
  do {                                                                \
    u16* d_ = &smB[((T) & 1) * 16384 + (((HALF) * 128 + w * 16) << 6)]; \
    const u16* s_ = Bs + (size_t)((HALF) * 128) * K + (size_t)(T) * 64; \
    gload16(s_, d_);                                                  \
    gload16(s_ + (size_t)8 * K, d_ + 8 * 64);                         \
  } while (0)

#define LDA(QM)                                                          \
  do {                                                                   \
    const u16* p_ = &smA[bi * 16384 + ((wr * 128 + (QM) * 64 + c5) << 6)]; \
    _Pragma("unroll") for (int s = 0; s < 4; ++s) {                      \
      const int sl_ = (((s << 1) | hi) ^ (c5 & 7)) << 3;                 \
      af[0][s] = *(const short8*)&p_[sl_];                               \
      af[1][s] = *(const short8*)&p_[32 * 64 + sl_];                     \
    }                                                                    \
  } while (0)

#define LDB(QN)                                                          \
  do {                                                                   \
    const u16* p_ = &smB[bi * 16384 + ((wc * 64 + (QN) * 32 + c5) << 6)]; \
    _Pragma("unroll") for (int s = 0; s < 4; ++s)                        \
      bf[QN][s] = *(const short8*)&p_[(((s << 1) | hi) ^ (c5 & 7)) << 3]; \
  } while (0)

#define MFMA_Q(QM, QN)                                                             \
  __builtin_amdgcn_s_setprio(1);                                                   \
  _Pragma("unroll") for (int s = 0; s < 4; ++s) {                                  \
    acc[(QM) * 2][(QN)] = __builtin_amdgcn_mfma_f32_32x32x16_bf16(                 \
        af[0][s], bf[QN][s], acc[(QM) * 2][(QN)], 0, 0, 0);                        \
    acc[(QM) * 2 + 1][(QN)] = __builtin_amdgcn_mfma_f32_32x32x16_bf16(             \
        af[1][s], bf[QN][s], acc[(QM) * 2 + 1][(QN)], 0, 0, 0);                    \
  }                                                                                \
  __builtin_amdgcn_s_setprio(0);

template <int MODE>
__global__ __launch_bounds__(512, 2) void gemm8p(
    const u16* __restrict__ A, const u16* __restrict__ B,
    const float* __restrict__ bq, const float* __restrict__ bk,
    const float* __restrict__ bvp, void* __restrict__ Cout,
    int M, int N, int K) {
  __shared__ u16 smA[2 * 16384];  // [buf][256 rows][64], 128B rows, 8x16B swizzled slots
  __shared__ u16 smB[2 * 16384];
  const int tid = threadIdx.x;
  const int w = tid >> 6, l = tid & 63;
  const int c5 = l & 31, hi = l >> 5;
  const int wr = w >> 2, wc = w & 3;

  // XCD-aware swizzle (nwg % 8 == 0 for all our launches)
  int flat = blockIdx.x + (int)gridDim.x * (int)blockIdx.y;
  const int nwg = (int)(gridDim.x * gridDim.y);
  flat = (flat & 7) * (nwg >> 3) + (flat >> 3);
  const int m0 = (flat / (int)gridDim.x) * 256, n0 = (flat % (int)gridDim.x) * 256;

  const int NSTEP = K / 64;
  f32x16 acc[4][2] = {};

  const int sgrp = l >> 3;
  const int scol = ((l & 7) ^ sgrp) * 8;
  const u16* As = A + (size_t)(m0 + w * 16 + sgrp) * K + scol;
  const u16* Bs = B + (size_t)(n0 + w * 16 + sgrp) * K + scol;

  STG_A(0, 0); STG_A(0, 1); STG_B(0, 0); STG_B(0, 1);
  STG_B(1, 0); STG_A(1, 0);
  asm volatile("s_waitcnt vmcnt(4)" ::: "memory");
  __builtin_amdgcn_s_barrier();

  short8 af[2][4], bf[2][4];
  for (int t = 0; t < NSTEP; ++t) {
    const int bi = t & 1;
    LDA(0); LDB(0);
    if (t + 1 < NSTEP) STG_B(t + 1, 1);
    __builtin_amdgcn_s_barrier();
    MFMA_Q(0, 0);
    __builtin_amdgcn_s_barrier();
    LDB(1);
    if (t + 1 < NSTEP) STG_A(t + 1, 1);
    __builtin_amdgcn_s_barrier();
    MFMA_Q(0, 1);
    __builtin_amdgcn_s_barrier();
    LDA(1);
    if (t + 2 < NSTEP) STG_B(t + 2, 0);
    __builtin_amdgcn_s_barrier();
    MFMA_Q(1, 1);
    __builtin_amdgcn_s_barrier();
    if (t + 2 < NSTEP) STG_A(t + 2, 0);
    __builtin_amdgcn_s_barrier();
    MFMA_Q(1, 0);
    if (t + 2 < NSTEP)
      asm volatile("s_waitcnt vmcnt(4)" ::: "memory");
    else if (t + 1 < NSTEP)
      asm volatile("s_waitcnt vmcnt(0)" ::: "memory");
    __builtin_amdgcn_s_barrier();
  }

#pragma unroll
  for (int nf = 0; nf < 2; ++nf) {
    const int col = n0 + wc * 64 + nf * 32 + c5;
    float bval, os;
    if (MODE == 0) {
      const int seg = col >> 11;
      const float* bp = seg == 0 ? bq : (seg == 1 ? bk : bvp);
      bval = bp[col & (DM - 1)];
      os = (seg == 0) ? QSCALE : 1.0f;
    } else {
      bval = bq[col];
      os = 1.0f;
    }
#pragma unroll
    for (int mf = 0; mf < 4; ++mf) {
#pragma unroll
      for (int r = 0; r < 16; ++r) {
        const int row = m0 + wr * 128 + mf * 32 + (r & 3) + 8 * (r >> 2) + 4 * hi;
        const float v = (acc[mf][nf][r] + bval) * os;
        if (MODE == 1)
          ((float*)Cout)[(size_t)row * N + col] = v;
        else
          ((u16*)Cout)[(size_t)row * N + col] = f2bf(v);
      }
    }
  }
}

// Flash attention: 8 waves x 32 q = 256 q/block, KV tiles of 64, 32x32x16 MFMA,
// swapped QK^T -> in-register softmax, P via cvt_pk + permlane32_swap.
// K AND V double-buffered, V XOR-swizzled [2][128][64] (write-early after QK),
// single barrier per tile, no LDS scratch (ds_bpermute for al / 1/l).
// LDS = 64 KiB exactly -> 2 blocks/CU resident.
__global__ __launch_bounds__(512, 2) void attn(
    const u16* __restrict__ QKV, u16* __restrict__ O) {
  __shared__ u16 smK[2 * 8192];   // [buf][kv 64][256B rows, 16x16B slots, ^row&15]
  __shared__ u16 smV[2 * 8192];   // [buf][d 128][64 kv], 128B rows, slot16 ^= d&7

  const u16* Qp = QKV;
  const u16* Kp = QKV + DM;
  const u16* Vp = QKV + 2 * DM;

  const int tid = threadIdx.x;
  const int w = tid >> 6, l = tid & 63;
  const int c5 = l & 31, hi = l >> 5;

  int flat = blockIdx.x + ((int)blockIdx.y << 3) + ((int)blockIdx.z << 7);
  flat = (flat & 7) * 64 + (flat >> 3);
  const int qt = flat & 7, h = (flat >> 3) & 15, b = flat >> 7;

  const int q0 = qt * 256 + w * 32;
  const size_t rowb = (size_t)b * SQ;
  const int hoff = h * DKH;

  short8 qf[8];
#pragma unroll
  for (int ds = 0; ds < 8; ++ds)
    qf[ds] = *(const short8*)&Qp[(rowb + q0 + c5) * LD3 + hoff + ds * 16 + hi * 8];

  f32x16 o[4] = {};
  float mrow = -1e30f, lsum = 0.f;

  const int vdg = tid >> 5;        // 0..15: d-block of 8
  const int kvp = (tid & 31) * 2;  // kv pair base
  u16x8 va, vb;

  // ---- prologue: K0 -> smK[0], V0 -> regs -> smV[0] (swizzled) ----
  {
#pragma unroll
    for (int uu = 0; uu < 2; ++uu) {
      const int u = w * 2 + uu;
      const int row = u * 4 + (l >> 4);
      const int col16 = (l & 15) ^ (row & 15);
      gload16(&Kp[(rowb + row) * LD3 + hoff + col16 * 8], &smK[u * 512]);
    }
    const u16* vp = &Vp[(rowb + kvp) * LD3 + hoff + vdg * 8];
    va = *(const u16x8*)vp;
    vb = *(const u16x8*)(vp + LD3);
#pragma unroll
    for (int i = 0; i < 8; ++i) {
      const int d = vdg * 8 + i;
      const int sl = (((kvp >> 3) ^ (d & 7)) << 3) + (kvp & 7);
      *(u32*)&smV[d * 64 + sl] = (u32)va[i] | ((u32)vb[i] << 16);
    }
  }
  __syncthreads();

  int buf = 0;
  for (int t = 0; t < NT; ++t) {
    const int nb = buf ^ 1;
    // ---- issue-early prefetch of tile t+1 (K via gload_lds, V to regs) ----
    if (t + 1 < NT) {
      const size_t kvr = rowb + (size_t)(t + 1) * KT;
#pragma unroll
      for (int uu = 0; uu < 2; ++uu) {
        const int u = w * 2 + uu;
        const int row = u * 4 + (l >> 4);
        const int col16 = (l & 15) ^ (row & 15);
        gload16(&Kp[(kvr + row) * LD3 + hoff + col16 * 8], &smK[nb * 8192 + u * 512]);
      }
      const u16* vp = &Vp[(kvr + kvp) * LD3 + hoff + vdg * 8];
      va = *(const u16x8*)vp;
      vb = *(const u16x8*)(vp + LD3);
    }

    // ---- S^T = mfma(K, Q) ----
    f32x16 s[2] = {};
    __builtin_amdgcn_s_setprio(1);
#pragma unroll
    for (int ni = 0; ni < 2; ++ni) {
      const int row = ni * 32 + c5;
#pragma unroll
      for (int ds = 0; ds < 8; ++ds) {
        const short8 kf = *(const short8*)&smK[buf * 8192 + row * 128 + (((ds << 1) | hi) ^ (row & 15)) * 8];
        s[ni] = __builtin_amdgcn_mfma_f32_32x32x16_bf16(kf, qf[ds], s[ni], 0, 0, 0);
      }
    }
    __builtin_amdgcn_s_setprio(0);

    // ---- write-early V(t+1) into smV[nb] (va/vb latency hidden under QK) ----
    if (t + 1 < NT) {
#pragma unroll
      for (int i = 0; i < 8; ++i) {
        const int d = vdg * 8 + i;
        const int sl = (((kvp >> 3) ^ (d & 7)) << 3) + (kvp & 7);
        *(u32*)&smV[nb * 8192 + d * 64 + sl] = (u32)va[i] | ((u32)vb[i] << 16);
      }
    }

    // ---- in-register online softmax (log2 domain; scale folded into Q) ----
    float mx = s[0][0];
#pragma unroll
    for (int ni = 0; ni < 2; ++ni)
#pragma unroll
      for (int i = 0; i < 16; ++i)
        mx = fmaxf(mx, s[ni][i]);
    i32x2 sw = __builtin_amdgcn_permlane32_swap(__float_as_int(mx), __float_as_int(mx), false, false);
    const float gmax = fmaxf(__int_as_float(sw.x), __int_as_float(sw.y));

    if (__any(gmax > mrow + 10.0f)) {
      const float mn = fmaxf(mrow, gmax);
      const float al = exp2f(mrow - mn);
      mrow = mn;
      lsum *= al;
      const int ali = __float_as_int(al);
#pragma unroll
      for (int r = 0; r < 16; ++r) {
        const int qloc = (r & 3) + 8 * (r >> 2) + 4 * hi;
        const float av = __int_as_float(__builtin_amdgcn_ds_bpermute(qloc * 4, ali));
#pragma unroll
        for (int dg = 0; dg < 4; ++dg) o[dg][r] *= av;
      }
    }

    float ps0 = 0.f, ps1 = 0.f;
#pragma unroll
    for (int i = 0; i < 16; ++i) {
      const float p0 = exp2f(s[0][i] - mrow);
      const float p1 = exp2f(s[1][i] - mrow);
      s[0][i] = p0; s[1][i] = p1;
      ps0 += p0; ps1 += p1;
    }
    lsum += ps0 + ps1;

    // ---- P -> A-frags (cvt_pk + permlane32_swap), then O += P V ----
    __builtin_amdgcn_s_setprio(1);
#pragma unroll
    for (int ks = 0; ks < 4; ++ks) {
      const int b0 = (ks & 1) * 8;
      const int ni = ks >> 1;
      const u32 A0 = cvtpk(s[ni][b0 + 0], s[ni][b0 + 1]);
      const u32 A1 = cvtpk(s[ni][b0 + 4], s[ni][b0 + 5]);
      const u32 B0 = cvtpk(s[ni][b0 + 2], s[ni][b0 + 3]);
      const u32 B1 = cvtpk(s[ni][b0 + 6], s[ni][b0 + 7]);
      const i32x2 r0 = __builtin_amdgcn_permlane32_swap((int)A0, (int)A1, false, false);
      const i32x2 r1 = __builtin_amdgcn_permlane32_swap((int)B0, (int)B1, false, false);
      u32x4 paw;
      paw.x = (u32)r0.x; paw.y = (u32)r1.x; paw.z = (u32)r0.y; paw.w = (u32)r1.y;
      const short8 pa = *(const short8*)&paw;
#pragma unroll
      for (int dg = 0; dg < 4; ++dg) {
        const int rowd = dg * 32 + c5;
        const short8 vf = *(const short8*)&smV[buf * 8192 + rowd * 64 + (((ks * 2 + hi) ^ (rowd & 7))) * 8];
        o[dg] = __builtin_amdgcn_mfma_f32_32x32x16_bf16(pa, vf, o[dg], 0, 0, 0);
      }
    }
    __builtin_amdgcn_s_setprio(0);

    // single barrier per tile: next tile's K/V reads + buffer swap become safe
    __syncthreads();
    buf = nb;
  }

  // ---- finalize: total l across halves, distribute via bpermute, store ----
  {
    const i32x2 sl = __builtin_amdgcn_permlane32_swap(__float_as_int(lsum), __float_as_int(lsum), false, false);
    const float tot = __int_as_float(sl.x) + __int_as_float(sl.y);
    const int invi = __float_as_int(1.0f / tot);
#pragma unroll
    for (int r = 0; r < 16; ++r) {
      const int qloc = (r & 3) + 8 * (r >> 2) + 4 * hi;
      const float inv = __int_as_float(__builtin_amdgcn_ds_bpermute(qloc * 4, invi));
      const size_t orow = (rowb + q0 + qloc) * DM + hoff;
#pragma unroll
      for (int dg = 0; dg < 4; ++dg)
        O[orow + dg * 32 + c5] = f2bf(o[dg][r] * inv);
    }
  }
}

extern "C" void kernel_launch(void* const* d_in, const int* in_sizes, int n_in,
                              void* d_out, int out_size, void* d_ws, size_t ws_size,
                              hipStream_t stream) {
  const float* x    = (const float*)d_in[0];
  const float* wq_w = (const float*)d_in[1];
  const float* wq_b = (const float*)d_in[2];
  const float* wk_w = (const float*)d_in[3];
  const float* wk_b = (const float*)d_in[4];
  const float* wv_w = (const float*)d_in[5];
  const float* wv_b = (const float*)d_in[6];
  const float* wo_w = (const float*)d_in[7];
  const float* wo_b = (const float*)d_in[8];
  float* out = (float*)d_out;

  u16* p = (u16*)d_ws;
  u16* xb  = p; p += (size_t)NB * SQ * DM;       // x (bf16), later reused as ctx
  u16* wqb = p; p += (size_t)3 * DM * DM;        // wq|wk|wv stacked (fused B)
  u16* wob = p; p += (size_t)DM * DM;
  u16* QKV = p; p += (size_t)NB * SQ * 3 * DM;   // fused [8192][6144] output
  u16* ctx = xb;

  const int nx = NB * SQ * DM;
  cvt_bf16<<<dim3(nx / 1024), dim3(256), 0, stream>>>(x, xb, nx);
  cvt_w4<<<dim3(DM * DM / 1024, 4), dim3(256), 0, stream>>>(wq_w, wk_w, wv_w, wo_w, wqb);

  // fused QKV projection: [8192][2048] @ [6144][2048]^T -> [8192][6144]
  dim3 gg3(3 * DM / 256, (NB * SQ) / 256);
  gemm8p<0><<<gg3, dim3(512), 0, stream>>>(xb, wqb, wq_b, wk_b, wv_b, QKV,
                                           NB * SQ, 3 * DM, DM);

  attn<<<dim3(SQ / 256, NH, NB), dim3(512), 0, stream>>>(QKV, ctx);

  dim3 ggo(DM / 256, (NB * SQ) / 256);
  gemm8p<1><<<ggo, dim3(512), 0, stream>>>(ctx, wob, wo_b, nullptr, nullptr, out,
                                           NB * SQ, DM, DM);
}